// Round 14
// baseline (62.062 us; speedup 1.0000x reference)
//
#include <hip/hip_runtime.h>
#include <hip/hip_fp16.h>

#define BATCH 8
#define CH 3
#define H_OUT 384
#define W_OUT 1280
#define H_IN 96
#define W_IN 320
#define HW_OUT (H_OUT * W_OUT)
#define HW_IN (H_IN * W_IN)

// block = 256 threads = 4 waves; each WAVE covers a 16x * 4y tile,
// block covers 64x * 4y. Grid = 8b * 96ys * 20xs = 15360.
#define XS_PER_ROW 20
#define YSEGS (H_OUT / 4)                 // 96
#define CHUNKS_PER_B (YSEGS * XS_PER_ROW) // 1920

#define LCOLS 18
#define LROWS 3

// row-pair packed image (no duplication): entry(b,k,cxi) = 16B
//   lo 8B = px(2k,   x=cxi-1) {c0,c1,c2,0} fp16
//   hi 8B = px(2k+1, x=cxi-1) {c0,c1,c2,0} fp16
// k = 0..191 pair-rows; cxi = 0 ghost(x=-1, zeros), 1..1280 -> x, 1281 ghost.
// One 128B line covers an 8x*2y source region (matches the 2x2 tap blob).
// Total 31.5 MB -> 3.94 MB/batch, fits one XCD's 4 MB L2.
#define NPAIR (H_OUT / 2)                 // 192
#define PSTRIDE 1282
#define PK_ENTRIES ((size_t)BATCH * NPAIR * PSTRIDE)
#define PK_BYTES (PK_ENTRIES * 16)

struct __attribute__((packed, aligned(4))) f2 { float x, y; };
struct __attribute__((packed, aligned(8))) u4 { unsigned int w[4]; };

// clang ext_vector float4 (usable with nontemporal builtins)
typedef float vf4 __attribute__((ext_vector_type(4)));

static __device__ __forceinline__ __half2 u2h2(unsigned int u) {
    return *reinterpret_cast<__half2*>(&u);
}
static __device__ __forceinline__ unsigned int h2u(__half2 h) {
    return *reinterpret_cast<unsigned int*>(&h);
}

// ---------------- pack: planar f32 -> row-pair interleaved fp16x4 ----------------
// XCD-affinity (b = bid&7) so batch b's packed lines live in XCD b's L2.
// 4 px/thread (one row-pair, 4 x positions): 6 NT float4 loads, 4x16B stores.
__global__ __launch_bounds__(256) void pack_pair_kernel(
    const float* __restrict__ image, __half* __restrict__ pk)
{
    int bid = blockIdx.x;              // 1920 blocks
    int b = bid & 7;
    int chunk = bid >> 3;              // 0..239
    int q = chunk * 256 + threadIdx.x; // 0..61439 = 192 pairs * 320 quads
    int k = q / 320;                   // pair-row
    int xq = (q - k * 320) * 4;        // x base (multiple of 4)

    const float* r0 = image + (size_t)b * (CH * HW_OUT) + (2 * k) * W_OUT + xq;
    const float* r1 = r0 + W_OUT;
    vf4 A0 = __builtin_nontemporal_load(reinterpret_cast<const vf4*>(r0));
    vf4 B0 = __builtin_nontemporal_load(reinterpret_cast<const vf4*>(r0 + HW_OUT));
    vf4 C0 = __builtin_nontemporal_load(reinterpret_cast<const vf4*>(r0 + 2 * HW_OUT));
    vf4 A1 = __builtin_nontemporal_load(reinterpret_cast<const vf4*>(r1));
    vf4 B1 = __builtin_nontemporal_load(reinterpret_cast<const vf4*>(r1 + HW_OUT));
    vf4 C1 = __builtin_nontemporal_load(reinterpret_cast<const vf4*>(r1 + 2 * HW_OUT));

    size_t e0 = ((size_t)(b * NPAIR + k) * PSTRIDE + (xq + 1));
    u4 e;
    e.w[0] = h2u(__floats2half2_rn(A0.x, B0.x));
    e.w[1] = h2u(__floats2half2_rn(C0.x, 0.0f));
    e.w[2] = h2u(__floats2half2_rn(A1.x, B1.x));
    e.w[3] = h2u(__floats2half2_rn(C1.x, 0.0f));
    *reinterpret_cast<u4*>(pk + e0 * 8) = e;
    e.w[0] = h2u(__floats2half2_rn(A0.y, B0.y));
    e.w[1] = h2u(__floats2half2_rn(C0.y, 0.0f));
    e.w[2] = h2u(__floats2half2_rn(A1.y, B1.y));
    e.w[3] = h2u(__floats2half2_rn(C1.y, 0.0f));
    *reinterpret_cast<u4*>(pk + (e0 + 1) * 8) = e;
    e.w[0] = h2u(__floats2half2_rn(A0.z, B0.z));
    e.w[1] = h2u(__floats2half2_rn(C0.z, 0.0f));
    e.w[2] = h2u(__floats2half2_rn(A1.z, B1.z));
    e.w[3] = h2u(__floats2half2_rn(C1.z, 0.0f));
    *reinterpret_cast<u4*>(pk + (e0 + 2) * 8) = e;
    e.w[0] = h2u(__floats2half2_rn(A0.w, B0.w));
    e.w[1] = h2u(__floats2half2_rn(C0.w, 0.0f));
    e.w[2] = h2u(__floats2half2_rn(A1.w, B1.w));
    e.w[3] = h2u(__floats2half2_rn(C1.w, 0.0f));
    *reinterpret_cast<u4*>(pk + (e0 + 3) * 8) = e;

    // ghost cols: entry 0 and 1281 of each (b,k) pair-row
    int gt = bid * 256 + threadIdx.x;
    if (gt < BATCH * NPAIR) {
        u4 z; z.w[0] = 0u; z.w[1] = 0u; z.w[2] = 0u; z.w[3] = 0u;
        size_t base = (size_t)gt * PSTRIDE;
        *reinterpret_cast<u4*>(pk + base * 8) = z;
        *reinterpret_cast<u4*>(pk + (base + 1281) * 8) = z;
    }
}

// ---------------- main kernel: 16x4 wave tiles ----------------
template <int MODE>   // 0 = planar f32 gathers, 1 = row-pair packed gathers
__global__ __launch_bounds__(256) void warp_sceneflow_kernel(
    const float* __restrict__ image,
    const __half* __restrict__ pk,
    const float* __restrict__ disp,
    const float* __restrict__ scene,
    const float* __restrict__ intrin,
    const float* __restrict__ aug,
    float* __restrict__ out)
{
    int bid = blockIdx.x;
    int b = bid & 7;                     // XCD-pinned batch
    int c = bid >> 3;                    // 0..1919
    int ys = c / XS_PER_ROW;
    int xs = c - ys * XS_PER_ROW;
    int ybase = ys * 4;
    int xbase = xs * 64;

    int tid = threadIdx.x;
    int wave = tid >> 6;                 // 0..3
    int lane = tid & 63;
    int x = xbase + wave * 16 + (lane & 15);   // wave footprint: 16x * 4y
    int y = ybase + (lane >> 4);

    // interleaved low-res LDS tile {disp,s0,s1,s2}
    __shared__ float4 lds4[LROWS][LCOLS];
    int ylo = (int)((float)ybase * ((float)(H_IN - 1) / (float)(H_OUT - 1)));
    int xlo = (int)((float)xbase * ((float)(W_IN - 1) / (float)(W_OUT - 1)));
    if (tid < LROWS * LCOLS) {
        int row = tid / LCOLS;
        int col = tid - row * LCOLS;
        int gy = min(ylo + row, H_IN - 1);
        int gx = min(xlo + col, W_IN - 1);
        int gi = gy * W_IN + gx;
        const float* dp = disp + b * HW_IN;
        const float* sp = scene + b * (CH * HW_IN);
        float4 v;
        v.x = dp[gi];
        v.y = sp[gi];
        v.z = sp[HW_IN + gi];
        v.w = sp[2 * HW_IN + gi];
        lds4[row][col] = v;
    }
    __syncthreads();

    float syr = (float)H_OUT / aug[b * 2 + 0];
    float sxr = (float)W_OUT / aug[b * 2 + 1];
    float fx = intrin[b * 9 + 0] * sxr;
    float fy = intrin[b * 9 + 4] * syr;
    float cx = intrin[b * 9 + 2] * sxr;
    float cy = intrin[b * 9 + 5] * syr;
    float inv_fx = 1.0f / fx;
    float inv_fy = 1.0f / fy;

    // low-res bilinear (from LDS)
    float xsrc = (float)x * ((float)(W_IN - 1) / (float)(W_OUT - 1));
    int x0 = (int)xsrc;
    float wx = xsrc - (float)x0;
    int lx = x0 - xlo;

    float ysrc = (float)y * ((float)(H_IN - 1) / (float)(H_OUT - 1));
    int y0 = (int)ysrc;
    float wy = ysrc - (float)y0;
    int ly = y0 - ylo;

    float4 t00 = lds4[ly][lx];
    float4 t01 = lds4[ly][lx + 1];
    float4 t10 = lds4[ly + 1][lx];
    float4 t11 = lds4[ly + 1][lx + 1];

    float w00 = (1.0f - wy) * (1.0f - wx);
    float w01 = (1.0f - wy) * wx;
    float w10 = wy * (1.0f - wx);
    float w11 = wy * wx;

    float dval = w00 * t00.x + w01 * t01.x + w10 * t10.x + w11 * t11.x;
    float sc0  = w00 * t00.y + w01 * t01.y + w10 * t10.y + w11 * t11.y;
    float sc1  = w00 * t00.z + w01 * t01.z + w10 * t10.z + w11 * t11.z;
    float sc2  = w00 * t00.w + w01 * t01.w + w10 * t10.w + w11 * t11.w;

    float disp_full = dval * (float)W_OUT;
    float depth = fminf(fmaxf(fx * 0.54f / (disp_full + 1e-8f), 0.001f), 80.0f);

    float X = ((float)x - cx) * inv_fx * depth + sc0;
    float Y = ((float)y - cy) * inv_fy * depth + sc1;
    float Z = depth + sc2;
    float u = fx * X + cx * Z;
    float v = fy * Y + cy * Z;
    float rw = 1.0f / (Z + 1e-8f);
    float gx = u * rw;                   // normalize round-trip elided (exact)
    float gy = v * rw;

    int ix0 = __float2int_rd(gx);
    int iy0 = __float2int_rd(gy);
    float fwx = gx - (float)ix0;
    float fwy = gy - (float)iy0;
    int ix1 = ix0 + 1, iy1 = iy0 + 1;
    bool vx0 = (ix0 >= 0) && (ix0 <= W_OUT - 1);
    bool vx1 = (ix1 >= 0) && (ix1 <= W_OUT - 1);
    bool vy0 = (iy0 >= 0) && (iy0 <= H_OUT - 1);
    bool vy1 = (iy1 >= 0) && (iy1 <= H_OUT - 1);
    float g00 = (1.0f - fwy) * (1.0f - fwx) * ((vx0 && vy0) ? 1.0f : 0.0f);
    float g01 = (1.0f - fwy) * fwx * ((vx1 && vy0) ? 1.0f : 0.0f);
    float g10 = fwy * (1.0f - fwx) * ((vx0 && vy1) ? 1.0f : 0.0f);
    float g11 = fwy * fwx * ((vx1 && vy1) ? 1.0f : 0.0f);
    int cy0 = min(max(iy0, 0), H_OUT - 1);
    int cy1 = min(max(iy1, 0), H_OUT - 1);

    float r0, r1, r2;
    if constexpr (MODE == 1) {
        int bxc = min(max(ix0, -1), W_OUT - 1);
        int cxi = bxc + 1;                       // 0..1280; x1 tap = cxi+1 <= 1281
        int pr0 = cy0 >> 1, p0 = cy0 & 1;
        int pr1 = cy1 >> 1, p1 = cy1 & 1;
        // half-index of an 8B pixel record: entry*8 + parity*4
        size_t h00 = ((size_t)(b * NPAIR + pr0) * PSTRIDE + cxi) * 8 + p0 * 4;
        size_t h10 = ((size_t)(b * NPAIR + pr1) * PSTRIDE + cxi) * 8 + p1 * 4;
        uint2 L00 = *reinterpret_cast<const uint2*>(pk + h00);      // (x0,y0)
        uint2 L01 = *reinterpret_cast<const uint2*>(pk + h00 + 8);  // (x1,y0)
        uint2 L10 = *reinterpret_cast<const uint2*>(pk + h10);      // (x0,y1)
        uint2 L11 = *reinterpret_cast<const uint2*>(pk + h10 + 8);  // (x1,y1)
        __half2 a00 = u2h2(L00.x), b00h = u2h2(L00.y);
        __half2 a01 = u2h2(L01.x), b01h = u2h2(L01.y);
        __half2 a10 = u2h2(L10.x), b10h = u2h2(L10.y);
        __half2 a11 = u2h2(L11.x), b11h = u2h2(L11.y);
        r0 = g00 * __low2float(a00) + g01 * __low2float(a01)
           + g10 * __low2float(a10) + g11 * __low2float(a11);
        r1 = g00 * __high2float(a00) + g01 * __high2float(a01)
           + g10 * __high2float(a10) + g11 * __high2float(a11);
        r2 = g00 * __low2float(b00h) + g01 * __low2float(b01h)
           + g10 * __low2float(b10h) + g11 * __low2float(b11h);
    } else {
        int cx0 = min(max(ix0, 0), W_OUT - 1);
        int cx1 = min(max(ix1, 0), W_OUT - 1);
        int xbi = min(cx0, W_OUT - 2);
        bool rcf = (cx0 != xbi);
        bool lcf = (cx1 == xbi);
        int rb0 = cy0 * W_OUT + xbi;
        int rb1 = cy1 * W_OUT + xbi;
        const float* ib = image + (size_t)b * (CH * HW_OUT);
        const float* im0 = ib;
        const float* im1 = ib + HW_OUT;
        const float* im2 = ib + 2 * HW_OUT;
        f2 P0 = *(const f2*)(im0 + rb0); f2 P1 = *(const f2*)(im0 + rb1);
        f2 Q0 = *(const f2*)(im1 + rb0); f2 Q1 = *(const f2*)(im1 + rb1);
        f2 T0 = *(const f2*)(im2 + rb0); f2 T1 = *(const f2*)(im2 + rb1);
        float p00 = rcf ? P0.y : P0.x, p01 = lcf ? P0.x : P0.y;
        float p10 = rcf ? P1.y : P1.x, p11 = lcf ? P1.x : P1.y;
        float q00 = rcf ? Q0.y : Q0.x, q01 = lcf ? Q0.x : Q0.y;
        float q10 = rcf ? Q1.y : Q1.x, q11 = lcf ? Q1.x : Q1.y;
        float t00f = rcf ? T0.y : T0.x, t01f = lcf ? T0.x : T0.y;
        float t10f = rcf ? T1.y : T1.x, t11f = lcf ? T1.x : T1.y;
        r0 = g00 * p00 + g01 * p01 + g10 * p10 + g11 * p11;
        r1 = g00 * q00 + g01 * q01 + g10 * q10 + g11 * q11;
        r2 = g00 * t00f + g01 * t01f + g10 * t10f + g11 * t11f;
    }

    float* ob = out + (size_t)b * (CH * HW_OUT);
    int op = y * W_OUT + x;
    __builtin_nontemporal_store(r0, ob + op);
    __builtin_nontemporal_store(r1, ob + HW_OUT + op);
    __builtin_nontemporal_store(r2, ob + 2 * HW_OUT + op);
}

extern "C" void kernel_launch(void* const* d_in, const int* in_sizes, int n_in,
                              void* d_out, int out_size, void* d_ws, size_t ws_size,
                              hipStream_t stream) {
    const float* image  = (const float*)d_in[0];
    const float* disp   = (const float*)d_in[1];
    const float* scene  = (const float*)d_in[2];
    const float* intrin = (const float*)d_in[3];
    const float* aug    = (const float*)d_in[4];
    float* out = (float*)d_out;

    const int grid = BATCH * CHUNKS_PER_B;  // 15360 blocks

    if (ws_size >= PK_BYTES) {
        __half* pk = (__half*)d_ws;
        pack_pair_kernel<<<BATCH * 240, 256, 0, stream>>>(image, pk);
        warp_sceneflow_kernel<1><<<grid, 256, 0, stream>>>(
            image, pk, disp, scene, intrin, aug, out);
    } else {
        warp_sceneflow_kernel<0><<<grid, 256, 0, stream>>>(
            image, nullptr, disp, scene, intrin, aug, out);
    }
}

// Round 15
// 52.438 us; speedup vs baseline: 1.1835x; 1.1835x over previous
//
#include <hip/hip_runtime.h>
#include <hip/hip_fp16.h>

#define BATCH 8
#define CH 3
#define H_OUT 384
#define W_OUT 1280
#define H_IN 96
#define W_IN 320
#define HW_OUT (H_OUT * W_OUT)
#define HW_IN (H_IN * W_IN)

// block = 256 threads = 4 waves; each WAVE covers a 16x * 4y tile,
// block covers 64x * 4y. Grid = 8b * 96ys * 20xs = 15360.
#define XS_PER_ROW 20
#define YSEGS (H_OUT / 4)                 // 96
#define CHUNKS_PER_B (YSEGS * XS_PER_ROW) // 1920

#define LCOLS 18
#define LROWS 3

// packed image: single-row fp16x4 {c0,c1,c2,0}, 8 B/px, stride 1282,
// 1-px front pad (base can be -1), ghost cols 1280/1281 zeroed.
// 3.95 MB/batch -> fits one XCD's 4 MB L2.
#define P1STRIDE 1282
#define P1_HALVES ((size_t)(1 + (size_t)BATCH * H_OUT * P1STRIDE) * 4)
#define P1_BYTES (P1_HALVES * 2)

struct __attribute__((packed, aligned(4))) f2 { float x, y; };
struct __attribute__((packed, aligned(8))) h8 { unsigned int w[4]; };
struct __attribute__((packed, aligned(8))) u4 { unsigned int w[4]; };

typedef float vf4 __attribute__((ext_vector_type(4)));

static __device__ __forceinline__ __half2 u2h2(unsigned int u) {
    return *reinterpret_cast<__half2*>(&u);
}
static __device__ __forceinline__ unsigned int h2u(__half2 h) {
    return *reinterpret_cast<unsigned int*>(&h);
}

// ---------------- pack: planar f32 -> strided interleaved fp16x4 ----------------
// XCD-affinity: b = bid&7 matches the warp kernel's mapping, so batch b's
// packed lines are written (and stay) in XCD b's L2, which re-reads them.
__global__ __launch_bounds__(256) void pack_single_kernel(
    const float* __restrict__ image, __half* __restrict__ pk)
{
    int bid = blockIdx.x;              // 3840 blocks
    int b = bid & 7;
    int chunk = bid >> 3;              // 0..479
    int p = chunk * 1024 + threadIdx.x * 4;
    int y = p / W_OUT;
    int x = p - y * W_OUT;             // multiple of 4

    const float* ib = image + (size_t)b * (CH * HW_OUT) + p;
    vf4 A  = __builtin_nontemporal_load(reinterpret_cast<const vf4*>(ib));
    vf4 Bv = __builtin_nontemporal_load(reinterpret_cast<const vf4*>(ib + HW_OUT));
    vf4 Cv = __builtin_nontemporal_load(reinterpret_cast<const vf4*>(ib + 2 * HW_OUT));

    u4 s0, s1;
    s0.w[0] = h2u(__floats2half2_rn(A.x, Bv.x));
    s0.w[1] = h2u(__floats2half2_rn(Cv.x, 0.0f));
    s0.w[2] = h2u(__floats2half2_rn(A.y, Bv.y));
    s0.w[3] = h2u(__floats2half2_rn(Cv.y, 0.0f));
    s1.w[0] = h2u(__floats2half2_rn(A.z, Bv.z));
    s1.w[1] = h2u(__floats2half2_rn(Cv.z, 0.0f));
    s1.w[2] = h2u(__floats2half2_rn(A.w, Bv.w));
    s1.w[3] = h2u(__floats2half2_rn(Cv.w, 0.0f));

    __half* pd = pk + 4;               // front pad = 1 pixel
    size_t off = ((size_t)(b * H_OUT + y) * P1STRIDE + x) * 4;
    *reinterpret_cast<u4*>(pd + off) = s0;
    *reinterpret_cast<u4*>(pd + off + 8) = s1;

    // ghost maintenance: cols 1280/1281 per row + front pad pixel
    int gt = bid * 256 + threadIdx.x;
    if (gt < BATCH * H_OUT) {
        uint2 z; z.x = 0u; z.y = 0u;
        size_t r = (size_t)gt;
        *reinterpret_cast<uint2*>(pd + (r * P1STRIDE + 1280) * 4) = z;
        *reinterpret_cast<uint2*>(pd + (r * P1STRIDE + 1281) * 4) = z;
        if (gt == 0) *reinterpret_cast<uint2*>(pk) = z;
    }
}

// ---------------- main kernel: 16x4 wave tiles ----------------
template <int MODE>   // 0 = planar f32 gathers, 1 = packed fp16x4 gathers
__global__ __launch_bounds__(256) void warp_sceneflow_kernel(
    const float* __restrict__ image,
    const __half* __restrict__ pk,
    const float* __restrict__ disp,
    const float* __restrict__ scene,
    const float* __restrict__ intrin,
    const float* __restrict__ aug,
    float* __restrict__ out)
{
    int bid = blockIdx.x;
    int b = bid & 7;                     // XCD-pinned batch
    int c = bid >> 3;                    // 0..1919
    int ys = c / XS_PER_ROW;
    int xs = c - ys * XS_PER_ROW;
    int ybase = ys * 4;
    int xbase = xs * 64;

    int tid = threadIdx.x;
    int wave = tid >> 6;                 // 0..3
    int lane = tid & 63;
    int x = xbase + wave * 16 + (lane & 15);   // wave footprint: 16x * 4y
    int y = ybase + (lane >> 4);

    // interleaved low-res LDS tile {disp,s0,s1,s2}
    __shared__ float4 lds4[LROWS][LCOLS];
    int ylo = (int)((float)ybase * ((float)(H_IN - 1) / (float)(H_OUT - 1)));
    int xlo = (int)((float)xbase * ((float)(W_IN - 1) / (float)(W_OUT - 1)));
    if (tid < LROWS * LCOLS) {
        int row = tid / LCOLS;
        int col = tid - row * LCOLS;
        int gy = min(ylo + row, H_IN - 1);
        int gx = min(xlo + col, W_IN - 1);
        int gi = gy * W_IN + gx;
        const float* dp = disp + b * HW_IN;
        const float* sp = scene + b * (CH * HW_IN);
        float4 v;
        v.x = dp[gi];
        v.y = sp[gi];
        v.z = sp[HW_IN + gi];
        v.w = sp[2 * HW_IN + gi];
        lds4[row][col] = v;
    }
    __syncthreads();

    float syr = (float)H_OUT / aug[b * 2 + 0];
    float sxr = (float)W_OUT / aug[b * 2 + 1];
    float fx = intrin[b * 9 + 0] * sxr;
    float fy = intrin[b * 9 + 4] * syr;
    float cx = intrin[b * 9 + 2] * sxr;
    float cy = intrin[b * 9 + 5] * syr;
    float inv_fx = 1.0f / fx;
    float inv_fy = 1.0f / fy;

    // low-res bilinear (from LDS)
    float xsrc = (float)x * ((float)(W_IN - 1) / (float)(W_OUT - 1));
    int x0 = (int)xsrc;
    float wx = xsrc - (float)x0;
    int lx = x0 - xlo;

    float ysrc = (float)y * ((float)(H_IN - 1) / (float)(H_OUT - 1));
    int y0 = (int)ysrc;
    float wy = ysrc - (float)y0;
    int ly = y0 - ylo;

    float4 t00 = lds4[ly][lx];
    float4 t01 = lds4[ly][lx + 1];
    float4 t10 = lds4[ly + 1][lx];
    float4 t11 = lds4[ly + 1][lx + 1];

    float w00 = (1.0f - wy) * (1.0f - wx);
    float w01 = (1.0f - wy) * wx;
    float w10 = wy * (1.0f - wx);
    float w11 = wy * wx;

    float dval = w00 * t00.x + w01 * t01.x + w10 * t10.x + w11 * t11.x;
    float sc0  = w00 * t00.y + w01 * t01.y + w10 * t10.y + w11 * t11.y;
    float sc1  = w00 * t00.z + w01 * t01.z + w10 * t10.z + w11 * t11.z;
    float sc2  = w00 * t00.w + w01 * t01.w + w10 * t10.w + w11 * t11.w;

    float disp_full = dval * (float)W_OUT;
    float depth = fminf(fmaxf(fx * 0.54f / (disp_full + 1e-8f), 0.001f), 80.0f);

    float X = ((float)x - cx) * inv_fx * depth + sc0;
    float Y = ((float)y - cy) * inv_fy * depth + sc1;
    float Z = depth + sc2;
    float u = fx * X + cx * Z;
    float v = fy * Y + cy * Z;
    float rw = 1.0f / (Z + 1e-8f);
    float gx = u * rw;                   // normalize round-trip elided (exact)
    float gy = v * rw;

    int ix0 = __float2int_rd(gx);
    int iy0 = __float2int_rd(gy);
    float fwx = gx - (float)ix0;
    float fwy = gy - (float)iy0;
    int ix1 = ix0 + 1, iy1 = iy0 + 1;
    bool vx0 = (ix0 >= 0) && (ix0 <= W_OUT - 1);
    bool vx1 = (ix1 >= 0) && (ix1 <= W_OUT - 1);
    bool vy0 = (iy0 >= 0) && (iy0 <= H_OUT - 1);
    bool vy1 = (iy1 >= 0) && (iy1 <= H_OUT - 1);
    float g00 = (1.0f - fwy) * (1.0f - fwx) * ((vx0 && vy0) ? 1.0f : 0.0f);
    float g01 = (1.0f - fwy) * fwx * ((vx1 && vy0) ? 1.0f : 0.0f);
    float g10 = fwy * (1.0f - fwx) * ((vx0 && vy1) ? 1.0f : 0.0f);
    float g11 = fwy * fwx * ((vx1 && vy1) ? 1.0f : 0.0f);
    int cy0 = min(max(iy0, 0), H_OUT - 1);
    int cy1 = min(max(iy1, 0), H_OUT - 1);

    float r0, r1, r2;
    if constexpr (MODE == 1) {
        int bx = min(max(ix0, -1), W_OUT - 1);
        const __half* pd = pk + 4;
        size_t rb0 = ((size_t)(b * H_OUT + cy0) * P1STRIDE + bx);
        size_t rb1 = ((size_t)(b * H_OUT + cy1) * P1STRIDE + bx);
        h8 L0 = *reinterpret_cast<const h8*>(pd + rb0 * 4);
        h8 L1 = *reinterpret_cast<const h8*>(pd + rb1 * 4);
        // packed blend: channels 0/1 via hfma2; channel 2 via hfma2 low half
        __half2 G00 = __float2half2_rn(g00);
        __half2 G01 = __float2half2_rn(g01);
        __half2 G10 = __float2half2_rn(g10);
        __half2 G11 = __float2half2_rn(g11);
        __half2 acc01 = __hmul2(G00, u2h2(L0.w[0]));        // x0,y0: c0c1
        acc01 = __hfma2(G01, u2h2(L0.w[2]), acc01);         // x1,y0
        acc01 = __hfma2(G10, u2h2(L1.w[0]), acc01);         // x0,y1
        acc01 = __hfma2(G11, u2h2(L1.w[2]), acc01);         // x1,y1
        __half2 acc2 = __hmul2(G00, u2h2(L0.w[1]));         // c2 in low
        acc2 = __hfma2(G01, u2h2(L0.w[3]), acc2);
        acc2 = __hfma2(G10, u2h2(L1.w[1]), acc2);
        acc2 = __hfma2(G11, u2h2(L1.w[3]), acc2);
        float2 f01 = __half22float2(acc01);
        r0 = f01.x;
        r1 = f01.y;
        r2 = __low2float(acc2);
    } else {
        int cx0 = min(max(ix0, 0), W_OUT - 1);
        int cx1 = min(max(ix1, 0), W_OUT - 1);
        int xbi = min(cx0, W_OUT - 2);
        bool rcf = (cx0 != xbi);
        bool lcf = (cx1 == xbi);
        int rb0 = cy0 * W_OUT + xbi;
        int rb1 = cy1 * W_OUT + xbi;
        const float* ib = image + (size_t)b * (CH * HW_OUT);
        const float* im0 = ib;
        const float* im1 = ib + HW_OUT;
        const float* im2 = ib + 2 * HW_OUT;
        f2 P0 = *(const f2*)(im0 + rb0); f2 P1 = *(const f2*)(im0 + rb1);
        f2 Q0 = *(const f2*)(im1 + rb0); f2 Q1 = *(const f2*)(im1 + rb1);
        f2 T0 = *(const f2*)(im2 + rb0); f2 T1 = *(const f2*)(im2 + rb1);
        float p00 = rcf ? P0.y : P0.x, p01 = lcf ? P0.x : P0.y;
        float p10 = rcf ? P1.y : P1.x, p11 = lcf ? P1.x : P1.y;
        float q00 = rcf ? Q0.y : Q0.x, q01 = lcf ? Q0.x : Q0.y;
        float q10 = rcf ? Q1.y : Q1.x, q11 = lcf ? Q1.x : Q1.y;
        float t00f = rcf ? T0.y : T0.x, t01f = lcf ? T0.x : T0.y;
        float t10f = rcf ? T1.y : T1.x, t11f = lcf ? T1.x : T1.y;
        r0 = g00 * p00 + g01 * p01 + g10 * p10 + g11 * p11;
        r1 = g00 * q00 + g01 * q01 + g10 * q10 + g11 * q11;
        r2 = g00 * t00f + g01 * t01f + g10 * t10f + g11 * t11f;
    }

    float* ob = out + (size_t)b * (CH * HW_OUT);
    int op = y * W_OUT + x;
    __builtin_nontemporal_store(r0, ob + op);
    __builtin_nontemporal_store(r1, ob + HW_OUT + op);
    __builtin_nontemporal_store(r2, ob + 2 * HW_OUT + op);
}

extern "C" void kernel_launch(void* const* d_in, const int* in_sizes, int n_in,
                              void* d_out, int out_size, void* d_ws, size_t ws_size,
                              hipStream_t stream) {
    const float* image  = (const float*)d_in[0];
    const float* disp   = (const float*)d_in[1];
    const float* scene  = (const float*)d_in[2];
    const float* intrin = (const float*)d_in[3];
    const float* aug    = (const float*)d_in[4];
    float* out = (float*)d_out;

    const int grid = BATCH * CHUNKS_PER_B;  // 15360 blocks

    if (ws_size >= P1_BYTES) {
        __half* pk = (__half*)d_ws;
        pack_single_kernel<<<BATCH * HW_OUT / 1024, 256, 0, stream>>>(image, pk);
        warp_sceneflow_kernel<1><<<grid, 256, 0, stream>>>(
            image, pk, disp, scene, intrin, aug, out);
    } else {
        warp_sceneflow_kernel<0><<<grid, 256, 0, stream>>>(
            image, nullptr, disp, scene, intrin, aug, out);
    }
}